// Round 4
// baseline (11647.776 us; speedup 1.0000x reference)
//
#include <hip/hip_runtime.h>
#include <hip/hip_bf16.h>

#define NN 100000
#define NE 1600000
#define DIM 128

using bf16 = __hip_bfloat16;
using bf162 = __hip_bfloat162;

// ---------- dtype helpers ----------
__device__ __forceinline__ float to_f(const float v) { return v; }
__device__ __forceinline__ float to_f(const bf16 v) { return __bfloat162float(v); }

__device__ __forceinline__ float4 ld4(const float* p) {
    return *reinterpret_cast<const float4*>(p);
}
__device__ __forceinline__ float4 ld4(const bf16* p) {
    const bf162* q = reinterpret_cast<const bf162*>(p);
    float2 a = __bfloat1622float2(q[0]);
    float2 b = __bfloat1622float2(q[1]);
    return make_float4(a.x, a.y, b.x, b.y);
}
__device__ __forceinline__ void st1(float* p, float v) { *p = v; }
__device__ __forceinline__ void st1(bf16* p, float v) { *p = __float2bfloat16(v); }

// ---------- degree / normalization ----------
__global__ void count_deg_k(const int* __restrict__ dst, float* __restrict__ cnt) {
    int i = blockIdx.x * blockDim.x + threadIdx.x;   // grid = NE exactly
    atomicAdd(&cnt[dst[i]], 1.0f);
}

__global__ void dinv_k(const float* __restrict__ cnt, float* __restrict__ dinv) {
    int i = blockIdx.x * blockDim.x + threadIdx.x;
    if (i < NN) dinv[i] = rsqrtf(cnt[i] + 1.0f);     // +1 self-loop
}

// ---------- edge scatter: agg[dst] += S[src]*dinv[s]*dinv[d] ----------
template <typename ST>
__global__ void scatter_k(const int* __restrict__ src, const int* __restrict__ dst,
                          const float* __restrict__ dinv, const ST* __restrict__ S,
                          float* __restrict__ agg) {
    int i = blockIdx.x * blockDim.x + threadIdx.x;   // grid = NE*32 exactly
    int e = i >> 5;
    int p = (i & 31) * 4;
    int s = src[e], d = dst[e];
    float nrm = dinv[s] * dinv[d];
    float4 hv = ld4(&S[(size_t)s * DIM + p]);
    float* ap = &agg[(size_t)d * DIM + p];
    atomicAdd(ap + 0, hv.x * nrm);
    atomicAdd(ap + 1, hv.y * nrm);
    atomicAdd(ap + 2, hv.z * nrm);
    atomicAdd(ap + 3, hv.w * nrm);
}

// ---------- fused GEMM: out = act((agg + S*dinv^2) @ W + b) ----------
// 8 rows per 256-thread block. agg/S/out may alias (in-place, same rows):
// each block reads only its own 8 rows into LDS before the barrier and
// writes only those rows after. NO __restrict__ on agg/S/out (they alias).
template <typename ST, typename OT, bool RELU>
__global__ __launch_bounds__(256) void gemm_fused_k(const float* agg, const ST* S,
                                                    const float* __restrict__ dinv,
                                                    const float* __restrict__ W,
                                                    const float* __restrict__ bias,
                                                    OT* out) {
    __shared__ float Ws[DIM * DIM];
    __shared__ float xs[8][DIM];
    __shared__ float bs[DIM];
    const int t = threadIdx.x;

#pragma unroll
    for (int i = 0; i < (DIM * DIM) / 256; ++i) Ws[t + i * 256] = W[t + i * 256];
    if (t < DIM) bs[t] = bias[t];

    const int r0 = blockIdx.x * 8;                   // grid = NN/8 exactly
#pragma unroll
    for (int i = 0; i < 4; ++i) {
        int idx = t + i * 256;
        int rr = idx >> 7, c = idx & 127;
        int r = r0 + rr;
        float di = dinv[r];
        size_t off = (size_t)r * DIM + c;
        xs[rr][c] = agg[off] + to_f(S[off]) * di * di;
    }
    __syncthreads();

    const int c  = t & 127;
    const int rb = (t >> 7) * 4;
    float a0 = 0.f, a1 = 0.f, a2 = 0.f, a3 = 0.f;
#pragma unroll 4
    for (int k = 0; k < DIM; ++k) {
        float w = Ws[k * DIM + c];
        a0 = fmaf(xs[rb + 0][k], w, a0);
        a1 = fmaf(xs[rb + 1][k], w, a1);
        a2 = fmaf(xs[rb + 2][k], w, a2);
        a3 = fmaf(xs[rb + 3][k], w, a3);
    }
    float b = bs[c];
    a0 += b; a1 += b; a2 += b; a3 += b;
    if (RELU) {
        a0 = fmaxf(a0, 0.f); a1 = fmaxf(a1, 0.f);
        a2 = fmaxf(a2, 0.f); a3 = fmaxf(a3, 0.f);
    }
    size_t o = (size_t)(r0 + rb) * DIM + c;
    st1(&out[o], a0);
    st1(&out[o + DIM], a1);
    st1(&out[o + 2 * DIM], a2);
    st1(&out[o + 3 * DIM], a3);
}

// ---------- tier-3 utilities ----------
__global__ void compress_k(const float* __restrict__ src, bf16* __restrict__ dst) {
    int i = blockIdx.x * blockDim.x + threadIdx.x;   // grid = NN*DIM/256 exactly
    dst[i] = __float2bfloat16(src[i]);
}
__global__ void decomp_k(float* __restrict__ dst, const bf16* __restrict__ src, int n) {
    int i = blockIdx.x * blockDim.x + threadIdx.x;
    if (i < n) dst[i] = __bfloat162float(src[i]);
}

// ---------- driver ----------
// ws layout: cnt @0 (400KB), dinv @512KiB (400KB), big region @1MiB (adaptive).
extern "C" void kernel_launch(void* const* d_in, const int* in_sizes, int n_in,
                              void* d_out, int out_size, void* d_ws, size_t ws_size,
                              hipStream_t stream) {
    const float* W0 = (const float*)d_in[4];
    const float* b0 = (const float*)d_in[5];
    const float* W1 = (const float*)d_in[6];
    const float* b1 = (const float*)d_in[7];

    char* ws = (char*)d_ws;
    float* cnt  = (float*)ws;
    float* dinv = (float*)(ws + (512u << 10));
    char*  big  = ws + (1u << 20);
    size_t big_avail = ws_size > (1u << 20) ? ws_size - (1u << 20) : 0;

    const size_t NB = (size_t)NN * DIM;              // 12.8M elements
    float* slot0 = (float*)d_out;
    float* slot1 = slot0 + NB;

    const int SG = (NE * 32) / 256;                  // scatter grid
    const int GG = NN / 8;                           // gemm grid

#define DEG(dstp)                                                        \
    do {                                                                 \
        hipMemsetAsync(cnt, 0, NN * sizeof(float), stream);              \
        count_deg_k<<<NE / 256, 256, 0, stream>>>((dstp), cnt);          \
        dinv_k<<<(NN + 255) / 256, 256, 0, stream>>>(cnt, dinv);         \
    } while (0)

    // ================= graph 0 (h0 lives in slot1, result in slot0) =================
    {
        const float* x  = (const float*)d_in[0];
        const int*   ei = (const int*)d_in[1];
        DEG(ei + NE);
        hipMemsetAsync(slot1, 0, NB * sizeof(float), stream);
        scatter_k<float><<<SG, 256, 0, stream>>>(ei, ei + NE, dinv, x, slot1);
        gemm_fused_k<float, float, true><<<GG, 256, 0, stream>>>(slot1, x, dinv, W0, b0, slot1);
        hipMemsetAsync(slot0, 0, NB * sizeof(float), stream);
        scatter_k<float><<<SG, 256, 0, stream>>>(ei, ei + NE, dinv, slot1, slot0);
        gemm_fused_k<float, float, false><<<GG, 256, 0, stream>>>(slot0, slot1, dinv, W1, b1, slot0);
    }

    // ================= graph 1 (needs one extra big buffer) =================
    {
        const float* x  = (const float*)d_in[2];
        const int*   ei = (const int*)d_in[3];

        if (big_avail >= NB * sizeof(float)) {
            // tier 1: fp32 H in ws
            float* H = (float*)big;
            DEG(ei + NE);
            hipMemsetAsync(H, 0, NB * sizeof(float), stream);
            scatter_k<float><<<SG, 256, 0, stream>>>(ei, ei + NE, dinv, x, H);
            gemm_fused_k<float, float, true><<<GG, 256, 0, stream>>>(H, x, dinv, W0, b0, H);
            hipMemsetAsync(slot1, 0, NB * sizeof(float), stream);
            scatter_k<float><<<SG, 256, 0, stream>>>(ei, ei + NE, dinv, H, slot1);
            gemm_fused_k<float, float, false><<<GG, 256, 0, stream>>>(slot1, H, dinv, W1, b1, slot1);
        } else if (big_avail >= NB * sizeof(bf16)) {
            // tier 2: bf16 H in ws
            bf16* H = (bf16*)big;
            DEG(ei + NE);
            hipMemsetAsync(slot1, 0, NB * sizeof(float), stream);
            scatter_k<float><<<SG, 256, 0, stream>>>(ei, ei + NE, dinv, x, slot1);
            gemm_fused_k<float, bf16, true><<<GG, 256, 0, stream>>>(slot1, x, dinv, W0, b0, H);
            hipMemsetAsync(slot1, 0, NB * sizeof(float), stream);
            scatter_k<bf16><<<SG, 256, 0, stream>>>(ei, ei + NE, dinv, H, slot1);
            gemm_fused_k<bf16, float, false><<<GG, 256, 0, stream>>>(slot1, H, dinv, W1, b1, slot1);
        } else {
            // tier 3: stash g0 as bf16 in slot1[0:NB), h1 as bf16 in slot1[NB:2NB) (bf16 idx)
            bf16* g0b = (bf16*)slot1;
            bf16* h1b = (bf16*)((char*)slot1 + NB * sizeof(bf16));
            compress_k<<<(int)(NB / 256), 256, 0, stream>>>(slot0, g0b);
            DEG(ei + NE);
            hipMemsetAsync(slot0, 0, NB * sizeof(float), stream);
            scatter_k<float><<<SG, 256, 0, stream>>>(ei, ei + NE, dinv, x, slot0);
            gemm_fused_k<float, bf16, true><<<GG, 256, 0, stream>>>(slot0, x, dinv, W0, b0, h1b);
            hipMemsetAsync(slot0, 0, NB * sizeof(float), stream);
            scatter_k<bf16><<<SG, 256, 0, stream>>>(ei, ei + NE, dinv, h1b, slot0);
            gemm_fused_k<bf16, float, false><<<GG, 256, 0, stream>>>(slot0, h1b, dinv, W1, b1, slot0);
            // swap: slot0 (g1) -> slot1, decompress g0b -> slot0. Descending chunks:
            // chunk reads of g0b (float-idx [a/2,(a+len)/2)) stay below prior writes [a+len,NB);
            // chunk writes to slot1 [a,a+len) only clobber g0b regions already consumed.
            float* stage = (float*)big;
            size_t C = (big_avail / sizeof(float)) & ~(size_t)255;
            if (C < 256) C = 256;                    // ws assumed >= ~1MiB + 1KB
            size_t a = NB;
            while (a > 0) {
                size_t len = (a >= C) ? C : a;
                a -= len;
                hipMemcpyAsync(stage, slot0 + a, len * sizeof(float),
                               hipMemcpyDeviceToDevice, stream);
                decomp_k<<<(int)((len + 255) / 256), 256, 0, stream>>>(slot0 + a, g0b + a, (int)len);
                hipMemcpyAsync(slot1 + a, stage, len * sizeof(float),
                               hipMemcpyDeviceToDevice, stream);
            }
        }
    }
#undef DEG
}

// Round 5
// 1625.746 us; speedup vs baseline: 7.1646x; 7.1646x over previous
//
#include <hip/hip_runtime.h>
#include <hip/hip_bf16.h>

#define NN 100000
#define NE 1600000
#define DIM 128
#define NBLK ((NN + 255) / 256)   // 391

using bf16 = __hip_bfloat16;
using bf162 = __hip_bfloat162;

// ---------- dtype helpers ----------
__device__ __forceinline__ float to_f(const float v) { return v; }
__device__ __forceinline__ float to_f(const bf16 v) { return __bfloat162float(v); }

__device__ __forceinline__ float4 ld4(const float* p) {
    return *reinterpret_cast<const float4*>(p);
}
__device__ __forceinline__ float4 ld4(const bf16* p) {
    const bf162* q = reinterpret_cast<const bf162*>(p);
    float2 a = __bfloat1622float2(q[0]);
    float2 b = __bfloat1622float2(q[1]);
    return make_float4(a.x, a.y, b.x, b.y);
}
__device__ __forceinline__ float2 ld2(const float* p) {
    return *reinterpret_cast<const float2*>(p);
}
__device__ __forceinline__ float2 ld2(const bf16* p) {
    return __bfloat1622float2(*reinterpret_cast<const bf162*>(p));
}
__device__ __forceinline__ void st1(float* p, float v) { *p = v; }
__device__ __forceinline__ void st1(bf16* p, float v) { *p = __float2bfloat16(v); }

// ---------- degree / normalization ----------
__global__ void count_deg_k(const int* __restrict__ dst, int* __restrict__ cnt) {
    int i = blockIdx.x * blockDim.x + threadIdx.x;   // grid = NE exactly
    atomicAdd(&cnt[dst[i]], 1);
}

__global__ void dinv_k(const int* __restrict__ cnt, float* __restrict__ dinv) {
    int i = blockIdx.x * blockDim.x + threadIdx.x;
    if (i < NN) dinv[i] = rsqrtf((float)cnt[i] + 1.0f);   // +1 self-loop
}

// ---------- CSR build: two-level exclusive scan + cursor fill ----------
__global__ void blocksum_k(const int* __restrict__ cnt, int* __restrict__ bsum) {
    __shared__ int s[256];
    int i = blockIdx.x * 256 + threadIdx.x;
    s[threadIdx.x] = (i < NN) ? cnt[i] : 0;
    __syncthreads();
    for (int off = 128; off > 0; off >>= 1) {
        if (threadIdx.x < off) s[threadIdx.x] += s[threadIdx.x + off];
        __syncthreads();
    }
    if (threadIdx.x == 0) bsum[blockIdx.x] = s[0];
}

__global__ void scan_bsum_k(const int* __restrict__ bsum, int* __restrict__ boff) {
    __shared__ int s[512];                           // 1 block of 512 covers NBLK=391
    int t = threadIdx.x;
    int v = (t < NBLK) ? bsum[t] : 0;
    s[t] = v;
    __syncthreads();
    for (int off = 1; off < 512; off <<= 1) {
        int tmp = (t >= off) ? s[t - off] : 0;
        __syncthreads();
        s[t] += tmp;
        __syncthreads();
    }
    if (t < NBLK) boff[t] = s[t] - v;                // exclusive
}

__global__ void scan_block_k(const int* __restrict__ cnt, const int* __restrict__ boff,
                             int* __restrict__ row_ptr, int* __restrict__ cursor) {
    __shared__ int s[256];
    int t = threadIdx.x, i = blockIdx.x * 256 + t;
    int v = (i < NN) ? cnt[i] : 0;
    s[t] = v;
    __syncthreads();
    for (int off = 1; off < 256; off <<= 1) {
        int tmp = (t >= off) ? s[t - off] : 0;
        __syncthreads();
        s[t] += tmp;
        __syncthreads();
    }
    if (i < NN) {
        int e = boff[blockIdx.x] + s[t] - v;         // global exclusive
        row_ptr[i] = e;
        cursor[i] = e;
    }
    if (i == NN - 1) row_ptr[NN] = NE;
}

__global__ void fill_k(const int* __restrict__ src, const int* __restrict__ dst,
                       int* __restrict__ cursor, int* __restrict__ csr_src) {
    int e = blockIdx.x * 256 + threadIdx.x;          // grid = NE exactly
    int d = dst[e];
    int pos = atomicAdd(&cursor[d], 1);
    csr_src[pos] = src[e];
}

// ---------- CSR gather: one wave per dst node, no atomics ----------
template <typename ST>
__global__ __launch_bounds__(256) void gather_k(const int* __restrict__ row_ptr,
                                                const int* __restrict__ csr_src,
                                                const float* __restrict__ dinv,
                                                const ST* __restrict__ h,
                                                float* __restrict__ agg) {
    int w = blockIdx.x * 4 + (threadIdx.x >> 6);     // node id; grid = NN/4 exactly
    if (w >= NN) return;
    int lane = threadIdx.x & 63;
    int beg = row_ptr[w], end = row_ptr[w + 1];
    float dd = dinv[w];
    float ax = 0.f, ay = 0.f;
    for (int base = beg; base < end; base += 64) {
        int k = end - base;
        if (k > 64) k = 64;
        int s = 0;
        float ns = 0.f;
        if (lane < k) { s = csr_src[base + lane]; ns = dinv[s]; }
        for (int j = 0; j < k; ++j) {
            int sj = __shfl(s, j);
            float nj = __shfl(ns, j);
            float2 hv = ld2(&h[(size_t)sj * DIM + lane * 2]);  // 512B/row coalesced
            ax = fmaf(hv.x, nj, ax);
            ay = fmaf(hv.y, nj, ay);
        }
    }
    ax *= dd;
    ay *= dd;
    reinterpret_cast<float2*>(&agg[(size_t)w * DIM])[lane] = make_float2(ax, ay);
}

// ---------- atomic scatter (fallback for tiny ws) ----------
template <typename ST>
__global__ void scatter_k(const int* __restrict__ src, const int* __restrict__ dst,
                          const float* __restrict__ dinv, const ST* __restrict__ S,
                          float* __restrict__ agg) {
    int i = blockIdx.x * blockDim.x + threadIdx.x;   // grid = NE*32 exactly
    int e = i >> 5;
    int p = (i & 31) * 4;
    int s = src[e], d = dst[e];
    float nrm = dinv[s] * dinv[d];
    float4 hv = ld4(&S[(size_t)s * DIM + p]);
    float* ap = &agg[(size_t)d * DIM + p];
    atomicAdd(ap + 0, hv.x * nrm);
    atomicAdd(ap + 1, hv.y * nrm);
    atomicAdd(ap + 2, hv.z * nrm);
    atomicAdd(ap + 3, hv.w * nrm);
}

// ---------- fused GEMM: out = act((agg + S*dinv^2) @ W + b) ----------
// 8 rows per 256-thread block; agg/S/out may alias row-wise (in-place safe).
template <typename ST, typename OT, bool RELU>
__global__ __launch_bounds__(256) void gemm_fused_k(const float* agg, const ST* S,
                                                    const float* __restrict__ dinv,
                                                    const float* __restrict__ W,
                                                    const float* __restrict__ bias,
                                                    OT* out) {
    __shared__ float Ws[DIM * DIM];
    __shared__ float xs[8][DIM];
    __shared__ float bs[DIM];
    const int t = threadIdx.x;

#pragma unroll
    for (int i = 0; i < (DIM * DIM) / 256; ++i) Ws[t + i * 256] = W[t + i * 256];
    if (t < DIM) bs[t] = bias[t];

    const int r0 = blockIdx.x * 8;                   // grid = NN/8 exactly
#pragma unroll
    for (int i = 0; i < 4; ++i) {
        int idx = t + i * 256;
        int rr = idx >> 7, c = idx & 127;
        int r = r0 + rr;
        float di = dinv[r];
        size_t off = (size_t)r * DIM + c;
        xs[rr][c] = agg[off] + to_f(S[off]) * di * di;
    }
    __syncthreads();

    const int c  = t & 127;
    const int rb = (t >> 7) * 4;
    float a0 = 0.f, a1 = 0.f, a2 = 0.f, a3 = 0.f;
#pragma unroll 4
    for (int k = 0; k < DIM; ++k) {
        float w = Ws[k * DIM + c];
        a0 = fmaf(xs[rb + 0][k], w, a0);
        a1 = fmaf(xs[rb + 1][k], w, a1);
        a2 = fmaf(xs[rb + 2][k], w, a2);
        a3 = fmaf(xs[rb + 3][k], w, a3);
    }
    float b = bs[c];
    a0 += b; a1 += b; a2 += b; a3 += b;
    if (RELU) {
        a0 = fmaxf(a0, 0.f); a1 = fmaxf(a1, 0.f);
        a2 = fmaxf(a2, 0.f); a3 = fmaxf(a3, 0.f);
    }
    size_t o = (size_t)(r0 + rb) * DIM + c;
    st1(&out[o], a0);
    st1(&out[o + DIM], a1);
    st1(&out[o + 2 * DIM], a2);
    st1(&out[o + 3 * DIM], a3);
}

// ---------- tier-3 utilities ----------
__global__ void compress_k(const float* __restrict__ src, bf16* __restrict__ dst) {
    int i = blockIdx.x * blockDim.x + threadIdx.x;   // grid = NB/256 exactly
    dst[i] = __float2bfloat16(src[i]);
}
__global__ void decomp_k(float* __restrict__ dst, const bf16* __restrict__ src, int n) {
    int i = blockIdx.x * blockDim.x + threadIdx.x;
    if (i < n) dst[i] = __bfloat162float(src[i]);
}

// ---------- driver ----------
// ws layout (CSR mode, needs >= 9 MiB):
//   cnt     @ 0        (400 KB, int)
//   dinv    @ 512 KiB  (400 KB)
//   row_ptr @ 1 MiB    (400 KB)
//   cursor  @ 1.5 MiB  (400 KB)
//   bsum    @ 2 MiB    (1.6 KB), boff @ 2 MiB + 4 KB
//   csr_src @ 2.25 MiB (6.4 MB)
//   big     @ 9 MiB    (graph-1 H tiers)
// Fallback mode (ws < 9 MiB): cnt/dinv as above, big @ 1 MiB, atomic scatter.
extern "C" void kernel_launch(void* const* d_in, const int* in_sizes, int n_in,
                              void* d_out, int out_size, void* d_ws, size_t ws_size,
                              hipStream_t stream) {
    const float* W0 = (const float*)d_in[4];
    const float* b0 = (const float*)d_in[5];
    const float* W1 = (const float*)d_in[6];
    const float* b1 = (const float*)d_in[7];

    char* ws = (char*)d_ws;
    int*   cnt  = (int*)ws;
    float* dinv = (float*)(ws + (512u << 10));
    int* row_ptr = (int*)(ws + (1u << 20));
    int* cursor  = (int*)(ws + (3u << 19));
    int* bsum    = (int*)(ws + (2u << 20));
    int* boff    = (int*)(ws + (2u << 20) + 4096);
    int* csr_src = (int*)(ws + (9u << 18));          // 2.25 MiB

    const bool csr_ok = ws_size >= (9u << 20);
    char* big = csr_ok ? ws + (9u << 20) : ws + (1u << 20);
    size_t big_avail = ws_size - (csr_ok ? (9u << 20) : (1u << 20));

    const size_t NB = (size_t)NN * DIM;
    float* slot0 = (float*)d_out;
    float* slot1 = slot0 + NB;

    const int SG = (NE * 32) / 256;
    const int GG = NN / 8;
    const int CG = NE / 256;

    auto build = [&](const int* srcp, const int* dstp) {
        hipMemsetAsync(cnt, 0, NN * sizeof(int), stream);
        count_deg_k<<<CG, 256, 0, stream>>>(dstp, cnt);
        dinv_k<<<(NN + 255) / 256, 256, 0, stream>>>(cnt, dinv);
        if (!csr_ok) return;
        blocksum_k<<<NBLK, 256, 0, stream>>>(cnt, bsum);
        scan_bsum_k<<<1, 512, 0, stream>>>(bsum, boff);
        scan_block_k<<<NBLK, 256, 0, stream>>>(cnt, boff, row_ptr, cursor);
        fill_k<<<CG, 256, 0, stream>>>(srcp, dstp, cursor, csr_src);
    };
    auto agg_f = [&](const int* srcp, const int* dstp, const float* h, float* agg) {
        if (csr_ok) {
            gather_k<float><<<NN / 4, 256, 0, stream>>>(row_ptr, csr_src, dinv, h, agg);
        } else {
            hipMemsetAsync(agg, 0, NB * sizeof(float), stream);
            scatter_k<float><<<SG, 256, 0, stream>>>(srcp, dstp, dinv, h, agg);
        }
    };
    auto agg_b = [&](const int* srcp, const int* dstp, const bf16* h, float* agg) {
        if (csr_ok) {
            gather_k<bf16><<<NN / 4, 256, 0, stream>>>(row_ptr, csr_src, dinv, h, agg);
        } else {
            hipMemsetAsync(agg, 0, NB * sizeof(float), stream);
            scatter_k<bf16><<<SG, 256, 0, stream>>>(srcp, dstp, dinv, h, agg);
        }
    };

    // ================= graph 0 (h in slot1, result in slot0) =================
    {
        const float* x  = (const float*)d_in[0];
        const int*   ei = (const int*)d_in[1];
        build(ei, ei + NE);
        agg_f(ei, ei + NE, x, slot1);
        gemm_fused_k<float, float, true><<<GG, 256, 0, stream>>>(slot1, x, dinv, W0, b0, slot1);
        agg_f(ei, ei + NE, slot1, slot0);
        gemm_fused_k<float, float, false><<<GG, 256, 0, stream>>>(slot0, slot1, dinv, W1, b1, slot0);
    }

    // ================= graph 1 =================
    {
        const float* x  = (const float*)d_in[2];
        const int*   ei = (const int*)d_in[3];
        build(ei, ei + NE);

        if (big_avail >= NB * sizeof(float)) {
            // tier 1: fp32 H in ws
            float* H = (float*)big;
            agg_f(ei, ei + NE, x, H);
            gemm_fused_k<float, float, true><<<GG, 256, 0, stream>>>(H, x, dinv, W0, b0, H);
            agg_f(ei, ei + NE, H, slot1);
            gemm_fused_k<float, float, false><<<GG, 256, 0, stream>>>(slot1, H, dinv, W1, b1, slot1);
        } else if (big_avail >= NB * sizeof(bf16)) {
            // tier 2: bf16 H in ws
            bf16* H = (bf16*)big;
            agg_f(ei, ei + NE, x, slot1);
            gemm_fused_k<float, bf16, true><<<GG, 256, 0, stream>>>(slot1, x, dinv, W0, b0, H);
            agg_b(ei, ei + NE, H, slot1);
            gemm_fused_k<bf16, float, false><<<GG, 256, 0, stream>>>(slot1, H, dinv, W1, b1, slot1);
        } else {
            // tier 3: stash g0 as bf16 in slot1 low half, h1 as bf16 in slot1 high half
            bf16* g0b = (bf16*)slot1;
            bf16* h1b = (bf16*)((char*)slot1 + NB * sizeof(bf16));
            compress_k<<<(int)(NB / 256), 256, 0, stream>>>(slot0, g0b);
            agg_f(ei, ei + NE, x, slot0);
            gemm_fused_k<float, bf16, true><<<GG, 256, 0, stream>>>(slot0, x, dinv, W0, b0, h1b);
            agg_b(ei, ei + NE, h1b, slot0);
            gemm_fused_k<bf16, float, false><<<GG, 256, 0, stream>>>(slot0, h1b, dinv, W1, b1, slot0);
            // swap: slot0 (g1) -> slot1, decompress g0b -> slot0, descending chunks.
            float* stage;
            size_t C;
            if (csr_ok) { stage = (float*)csr_src; C = 1600000; }   // CSR dead now
            else {
                stage = (float*)big;
                C = (big_avail / sizeof(float)) & ~(size_t)255;
                if (C < 256) C = 256;
            }
            size_t a = NB;
            while (a > 0) {
                size_t len = (a >= C) ? C : a;
                a -= len;
                hipMemcpyAsync(stage, slot0 + a, len * sizeof(float),
                               hipMemcpyDeviceToDevice, stream);
                decomp_k<<<(int)((len + 255) / 256), 256, 0, stream>>>(slot0 + a, g0b + a, (int)len);
                hipMemcpyAsync(slot1 + a, stage, len * sizeof(float),
                               hipMemcpyDeviceToDevice, stream);
            }
        }
    }
}